// Round 1
// baseline (363.400 us; speedup 1.0000x reference)
//
#include <hip/hip_runtime.h>
#include <cstdint>
#include <cstddef>

#define TOK 4096
#define DM 768
#define HID 2048
#define NE 8

typedef __attribute__((ext_vector_type(8))) short bf16x8;
typedef __attribute__((ext_vector_type(4))) float f32x4;

// async global->LDS: dest = wave-uniform base + lane*16; SOURCE is per-lane.
#define ASYNC16(GP, LP) \
  __builtin_amdgcn_global_load_lds((__attribute__((address_space(1))) void*)(GP), \
                                   (__attribute__((address_space(3))) void*)(LP), 16, 0, 0)

__device__ __forceinline__ unsigned short f2bf(float f) {
  unsigned int u = __float_as_uint(f);
  u += 0x7FFF + ((u >> 16) & 1);   // RNE
  return (unsigned short)(u >> 16);
}
__device__ __forceinline__ unsigned int pack2(float a, float b) {
  return (unsigned)f2bf(a) | ((unsigned)f2bf(b) << 16);
}
__device__ __forceinline__ int padded_off(const int* counts, int e) {
  int o = 0;
  for (int i = 0; i < e; ++i) o += (counts[i] + 127) & ~127;
  return o;
}

// ---------------- K_gate: gating only (NO atomics) ----------------
__global__ __launch_bounds__(256)
void k_gate(const float* __restrict__ x, const float* __restrict__ wgw,
            const float* __restrict__ wgb,
            int* __restrict__ eidx, float* __restrict__ gatep,
            float* __restrict__ cepart)
{
  __shared__ float ce_loc[4][NE];
  const int lane = threadIdx.x & 63;
  const int w = threadIdx.x >> 6;
  const int t = blockIdx.x * 4 + w;
  float acc[NE];
#pragma unroll
  for (int e = 0; e < NE; ++e) acc[e] = 0.f;
  const float* xr = x + (size_t)t * DM;
#pragma unroll
  for (int j = 0; j < DM / 64; ++j) {
    float xv = xr[j * 64 + lane];
#pragma unroll
    for (int e = 0; e < NE; ++e) acc[e] += xv * wgw[e * DM + j * 64 + lane];
  }
#pragma unroll
  for (int e = 0; e < NE; ++e) {
    float v = acc[e];
#pragma unroll
    for (int off = 32; off >= 1; off >>= 1) v += __shfl_xor(v, off);
    acc[e] = v + wgb[e];
  }
  float mx = acc[0]; int ai = 0;
#pragma unroll
  for (int e = 1; e < NE; ++e) if (acc[e] > mx) { mx = acc[e]; ai = e; }
  float p[NE]; float se = 0.f;
#pragma unroll
  for (int e = 0; e < NE; ++e) { p[e] = expf(acc[e] - mx); se += p[e]; }
  float inv = 1.f / se;
  if (lane == 0) {
#pragma unroll
    for (int e = 0; e < NE; ++e) ce_loc[w][e] = p[e] * inv;
    eidx[t] = ai;
    gatep[t] = p[ai] * inv;
  }
  __syncthreads();
  if (threadIdx.x < NE) {
    float s = ce_loc[0][threadIdx.x] + ce_loc[1][threadIdx.x]
            + ce_loc[2][threadIdx.x] + ce_loc[3][threadIdx.x];
    cepart[blockIdx.x * NE + threadIdx.x] = s;
  }
}

// ---------------- K_count: single-block counting sort + aux ----------------
__global__ __launch_bounds__(256)
void k_count(const int* __restrict__ eidx, const float* __restrict__ gatep,
             const float* __restrict__ cepart,
             int* __restrict__ prow_arr, int* __restrict__ tlist,
             float* __restrict__ gate_b, int* __restrict__ counts_g,
             float* __restrict__ aux_out)
{
  __shared__ int hist[256][NE];
  __shared__ float fs[256][NE];
  __shared__ int po_s[NE], cnt_s[NE];
  const int tid = threadIdx.x;
  int own[NE], v[NE], el[16];
#pragma unroll
  for (int e = 0; e < NE; ++e) own[e] = 0;
#pragma unroll
  for (int j = 0; j < 16; ++j) {
    el[j] = eidx[tid * 16 + j];
#pragma unroll
    for (int e = 0; e < NE; ++e) own[e] += (el[j] == e) ? 1 : 0;
  }
#pragma unroll
  for (int e = 0; e < NE; ++e) { v[e] = own[e]; hist[tid][e] = v[e]; }
  __syncthreads();
  for (int st = 1; st < 256; st <<= 1) {
    int add[NE];
#pragma unroll
    for (int e = 0; e < NE; ++e) add[e] = (tid >= st) ? hist[tid - st][e] : 0;
    __syncthreads();
#pragma unroll
    for (int e = 0; e < NE; ++e) { v[e] += add[e]; hist[tid][e] = v[e]; }
    __syncthreads();
  }
  if (tid == 0) {
    int o = 0;
#pragma unroll
    for (int e = 0; e < NE; ++e) {
      int c = hist[255][e];
      cnt_s[e] = c; counts_g[e] = c; po_s[e] = o;
      o += (c + 127) & ~127;
    }
  }
  __syncthreads();
  int run[NE];
#pragma unroll
  for (int e = 0; e < NE; ++e) run[e] = po_s[e] + v[e] - own[e];
#pragma unroll
  for (int j = 0; j < 16; ++j) {
    const int t = tid * 16 + j;
    const int e = el[j];
    int p = 0;
#pragma unroll
    for (int k = 0; k < NE; ++k) if (e == k) p = run[k]++;
    prow_arr[t] = p;
    tlist[p] = t;
    gate_b[p] = gatep[t];
  }
  // aux reduce
  float s[NE];
#pragma unroll
  for (int e = 0; e < NE; ++e) s[e] = 0.f;
  for (int bb = tid; bb < 1024; bb += 256)
#pragma unroll
    for (int e = 0; e < NE; ++e) s[e] += cepart[bb * NE + e];
#pragma unroll
  for (int e = 0; e < NE; ++e) fs[tid][e] = s[e];
  __syncthreads();
  for (int st = 128; st > 0; st >>= 1) {
    if (tid < st)
#pragma unroll
      for (int e = 0; e < NE; ++e) fs[tid][e] += fs[tid + st][e];
    __syncthreads();
  }
  if (tid == 0) {
    float aux = 0.f;
    for (int e = 0; e < NE; ++e)
      aux += ((float)cnt_s[e] / 4096.f) * (fs[0][e] / 4096.f);
    aux_out[0] = 0.05f * 8.f * aux;
  }
}

// ---------------- K2: scatter x rows (row-major bf16) + zero y ----------------
__global__ __launch_bounds__(256)
void k2_scatter_zero(const float* __restrict__ x, const int* __restrict__ prow_arr,
                     unsigned short* __restrict__ xb, float* __restrict__ y)
{
  const int b = blockIdx.x;
  if (b < 1024) {
    const int lane = threadIdx.x & 63;
    const int w = threadIdx.x >> 6;
    const int t = b * 4 + w;
    const int prow = prow_arr[t];
    const float4* src4 = (const float4*)(x + (size_t)t * DM);
    uint2* dst = (uint2*)(xb + (size_t)prow * DM);
#pragma unroll
    for (int c = 0; c < 3; ++c) {
      float4 v = src4[lane + c * 64];
      uint2 d; d.x = pack2(v.x, v.y); d.y = pack2(v.z, v.w);
      dst[lane + c * 64] = d;
    }
  } else {
    float4* y4 = (float4*)y;
    const int base = (b - 1024) * 1536 + threadIdx.x;
#pragma unroll
    for (int c = 0; c < 6; ++c) {
      float4 z; z.x = 0.f; z.y = 0.f; z.z = 0.f; z.w = 0.f;
      y4[base + c * 256] = z;
    }
  }
}

// ---------------- FFN1: h = silu(x@Wu)*(x@Wv)*gate ----------------
// Fused fp32->bf16 conversion. 256M x 128N, BK=32, double-buffered.
// 512 threads = 8 waves (4m x 2n), wave tile 64x64.
// LDS per buffer: A 16KB | Bu 8KB | Bv 8KB  (2 buffers = 64KB).
// LDS swizzle: unit (r, slot) at (r*4+slot)*16B holds k-octet
// (slot - r - (r>>2)) & 3  -> read with slot=(q + r + (r>>2))&3.
// Per 8-lane phase of a b128 op this hits all 8 bank groups (conflict-free).
__global__ __launch_bounds__(512, 2)
void k_ffn1(const float* __restrict__ Wu, const float* __restrict__ Wv,
            const unsigned short* __restrict__ xb, const float* __restrict__ gate_b,
            const int* __restrict__ counts, unsigned short* __restrict__ h)
{
  const int bid = blockIdx.x;
  const int e = bid & 7;                 // expert -> XCD pin (round-robin heuristic)
  const int r_ = bid >> 3;
  const int tm = r_ & 15;
  const int tn = r_ >> 4;                // 0..15
  const int Me = counts[e];
  if (tm * 256 >= Me) return;
  const int prowbase = padded_off(counts, e) + tm * 256;

  __shared__ __align__(16) char Sh[65536];   // [2][A 16K | Bu 8K | Bv 8K]

  const int tid = threadIdx.x;
  const int lane = tid & 63;
  const int w = tid >> 6;
  const int wm = w >> 1, wn = w & 1;

  // ---- A async staging: 2 chunks of 1KB per wave (16 chunks = 256 rows x 32k)
  const int c0 = w * 2, c1 = w * 2 + 1;
  const int mA0 = c0 * 16 + (lane >> 2), sA0 = lane & 3;
  const int ko0 = (sA0 - mA0 - (mA0 >> 2)) & 3;
  const char* aSrc0 = (const char*)xb + (size_t)(prowbase + mA0) * (DM * 2) + ko0 * 16;
  const int mA1 = c1 * 16 + (lane >> 2), sA1 = lane & 3;
  const int ko1 = (sA1 - mA1 - (mA1 >> 2)) & 3;
  const char* aSrc1 = (const char*)xb + (size_t)(prowbase + mA1) * (DM * 2) + ko1 * 16;

  // ---- B reg-staging: thread -> (nloc, koW); 8 coalesced fp32 loads (256B/wave)
  const int koW = w & 3;
  const int nloc = (w >> 2) * 64 + lane;
  const unsigned offBw = (unsigned)(nloc * 4 + ((koW + nloc + (nloc >> 2)) & 3)) * 16;
  const int ncol = tn * 128 + nloc;
  const float* srcU = Wu + (size_t)e * DM * HID + (size_t)(koW * 8) * HID + ncol;
  const float* srcV = Wv + (size_t)e * DM * HID + (size_t)(koW * 8) * HID + ncol;

  // ---- compute-side LDS read offsets
  const int lc = lane & 15, q = lane >> 4;
  unsigned offA[4], offU[4], offV[4];
#pragma unroll
  for (int i = 0; i < 4; ++i) {
    int m = wm * 64 + i * 16 + lc;
    offA[i] = (unsigned)(m * 4 + ((q + m + (m >> 2)) & 3)) * 16;
    int n = wn * 64 + i * 16 + lc;
    unsigned ob = (unsigned)(n * 4 + ((q + n + (n >> 2)) & 3)) * 16;
    offU[i] = 16384u + ob;
    offV[i] = 24576u + ob;
  }

  f32x4 accU[4][4], accV[4][4];
#pragma unroll
  for (int i = 0; i < 4; ++i)
#pragma unroll
    for (int j = 0; j < 4; ++j)
#pragma unroll
      for (int k = 0; k < 4; ++k) { accU[i][j][k] = 0.f; accV[i][j][k] = 0.f; }

  float fu[8], fv[8];
  // ---- prologue: stage step 0 into buffer 0
  ASYNC16(aSrc0, Sh + c0 * 1024); aSrc0 += 64;
  ASYNC16(aSrc1, Sh + c1 * 1024); aSrc1 += 64;
#pragma unroll
  for (int j = 0; j < 8; ++j) { fu[j] = srcU[(size_t)j * HID]; fv[j] = srcV[(size_t)j * HID]; }
  srcU += (size_t)32 * HID; srcV += (size_t)32 * HID;
  {
    uint4 up, vp;
    up.x = pack2(fu[0], fu[1]); up.y = pack2(fu[2], fu[3]);
    up.z = pack2(fu[4], fu[5]); up.w = pack2(fu[6], fu[7]);
    vp.x = pack2(fv[0], fv[1]); vp.y = pack2(fv[2], fv[3]);
    vp.z = pack2(fv[4], fv[5]); vp.w = pack2(fv[6], fv[7]);
    *(uint4*)(Sh + 16384 + offBw) = up;
    *(uint4*)(Sh + 24576 + offBw) = vp;
  }
  __syncthreads();

  for (int kt = 0; kt < 24; ++kt) {
    char* bufc = Sh + (unsigned)(kt & 1) * 32768u;
    char* bufn = Sh + (unsigned)((kt + 1) & 1) * 32768u;
    const bool more = (kt + 1) < 24;
    if (more) {                       // issue next step's loads BEFORE compute
      ASYNC16(aSrc0, bufn + c0 * 1024); aSrc0 += 64;
      ASYNC16(aSrc1, bufn + c1 * 1024); aSrc1 += 64;
#pragma unroll
      for (int j = 0; j < 8; ++j) { fu[j] = srcU[(size_t)j * HID]; fv[j] = srcV[(size_t)j * HID]; }
      srcU += (size_t)32 * HID; srcV += (size_t)32 * HID;
    }
    bf16x8 a[4], bu[4], bv[4];
#pragma unroll
    for (int i = 0; i < 4; ++i) a[i] = *(const bf16x8*)(bufc + offA[i]);
#pragma unroll
    for (int j = 0; j < 4; ++j) {
      bu[j] = *(const bf16x8*)(bufc + offU[j]);
      bv[j] = *(const bf16x8*)(bufc + offV[j]);
    }
#pragma unroll
    for (int i = 0; i < 4; ++i)
#pragma unroll
      for (int j = 0; j < 4; ++j) {
        accU[i][j] = __builtin_amdgcn_mfma_f32_16x16x32_bf16(a[i], bu[j], accU[i][j], 0, 0, 0);
        accV[i][j] = __builtin_amdgcn_mfma_f32_16x16x32_bf16(a[i], bv[j], accV[i][j], 0, 0, 0);
      }
    if (more) {                       // convert + write next buffer (latency hidden by MFMA)
      uint4 up, vp;
      up.x = pack2(fu[0], fu[1]); up.y = pack2(fu[2], fu[3]);
      up.z = pack2(fu[4], fu[5]); up.w = pack2(fu[6], fu[7]);
      vp.x = pack2(fv[0], fv[1]); vp.y = pack2(fv[2], fv[3]);
      vp.z = pack2(fv[4], fv[5]); vp.w = pack2(fv[6], fv[7]);
      *(uint4*)(bufn + 16384 + offBw) = up;
      *(uint4*)(bufn + 24576 + offBw) = vp;
    }
    __syncthreads();
  }

  const int colbase = tn * 128 + wn * 64;
  const int rlane = (lane >> 4) * 4;
  const int clane = lane & 15;
#pragma unroll
  for (int i = 0; i < 4; ++i) {
#pragma unroll
    for (int rr = 0; rr < 4; ++rr) {
      int rowIn = wm * 64 + i * 16 + rlane + rr;
      if (tm * 256 + rowIn < Me) {
        int prow = prowbase + rowIn;
        float g = gate_b[prow];
        unsigned short* hp = h + (size_t)prow * HID + colbase + clane;
#pragma unroll
        for (int j = 0; j < 4; ++j) {
          float u_ = accU[i][j][rr];
          float v_ = accV[i][j][rr];
          float sv = u_ / (1.f + expf(-u_));
          hp[j * 16] = f2bf(sv * v_ * g);
        }
      }
    }
  }
}

// ---------------- FFN2: y += h @ Wd (split-K=4, atomic f32) ----------------
// Fused fp32->bf16 conversion. 256M x 128N, BK=32, double-buffered.
// LDS per buffer: A 16KB | B 8KB  (2 buffers = 48KB).
__global__ __launch_bounds__(512, 2)
void k_ffn2(const float* __restrict__ Wd, const unsigned short* __restrict__ h,
            const int* __restrict__ counts, const int* __restrict__ tlist,
            float* __restrict__ y)
{
  const int bid = blockIdx.x;
  const int e = bid & 7;                 // expert -> XCD pin
  int r_ = bid >> 3;
  const int tn = r_ % 6; r_ /= 6;        // 0..5
  const int sk = r_ & 3;                 // split-K 0..3
  const int tm = r_ >> 2;                // 0..15
  const int Me = counts[e];
  if (tm * 256 >= Me) return;
  const int prowbase = padded_off(counts, e) + tm * 256;

  __shared__ __align__(16) char Sh[49152];   // [2][A 16K | B 8K]

  const int tid = threadIdx.x;
  const int lane = tid & 63;
  const int w = tid >> 6;
  const int wm = w >> 1, wn = w & 1;

  // ---- A async staging (h rows, bf16), split-K window
  const int c0 = w * 2, c1 = w * 2 + 1;
  const int mA0 = c0 * 16 + (lane >> 2), sA0 = lane & 3;
  const int ko0 = (sA0 - mA0 - (mA0 >> 2)) & 3;
  const char* aSrc0 = (const char*)h + (size_t)(prowbase + mA0) * (HID * 2) + sk * 1024 + ko0 * 16;
  const int mA1 = c1 * 16 + (lane >> 2), sA1 = lane & 3;
  const int ko1 = (sA1 - mA1 - (mA1 >> 2)) & 3;
  const char* aSrc1 = (const char*)h + (size_t)(prowbase + mA1) * (HID * 2) + sk * 1024 + ko1 * 16;

  // ---- B reg-staging: one 16B unit per thread
  const int nloc = tid & 127;
  const int koW = tid >> 7;              // 0..3
  const unsigned offBw = (unsigned)(nloc * 4 + ((koW + nloc + (nloc >> 2)) & 3)) * 16;
  const int ncol = tn * 128 + nloc;
  const float* srcD = Wd + (size_t)e * HID * DM + (size_t)(sk * 512 + koW * 8) * DM + ncol;

  const int lc = lane & 15, q = lane >> 4;
  unsigned offA[4], offBr[4];
#pragma unroll
  for (int i = 0; i < 4; ++i) {
    int m = wm * 64 + i * 16 + lc;
    offA[i] = (unsigned)(m * 4 + ((q + m + (m >> 2)) & 3)) * 16;
    int n = wn * 64 + i * 16 + lc;
    offBr[i] = 16384u + (unsigned)(n * 4 + ((q + n + (n >> 2)) & 3)) * 16;
  }

  f32x4 acc[4][4];
#pragma unroll
  for (int i = 0; i < 4; ++i)
#pragma unroll
    for (int j = 0; j < 4; ++j)
#pragma unroll
      for (int k = 0; k < 4; ++k) acc[i][j][k] = 0.f;

  float fd[8];
  // ---- prologue
  ASYNC16(aSrc0, Sh + c0 * 1024); aSrc0 += 64;
  ASYNC16(aSrc1, Sh + c1 * 1024); aSrc1 += 64;
#pragma unroll
  for (int j = 0; j < 8; ++j) fd[j] = srcD[(size_t)j * DM];
  srcD += (size_t)32 * DM;
  {
    uint4 dp;
    dp.x = pack2(fd[0], fd[1]); dp.y = pack2(fd[2], fd[3]);
    dp.z = pack2(fd[4], fd[5]); dp.w = pack2(fd[6], fd[7]);
    *(uint4*)(Sh + 16384 + offBw) = dp;
  }
  __syncthreads();

  for (int kt = 0; kt < 16; ++kt) {
    char* bufc = Sh + (unsigned)(kt & 1) * 24576u;
    char* bufn = Sh + (unsigned)((kt + 1) & 1) * 24576u;
    const bool more = (kt + 1) < 16;
    if (more) {
      ASYNC16(aSrc0, bufn + c0 * 1024); aSrc0 += 64;
      ASYNC16(aSrc1, bufn + c1 * 1024); aSrc1 += 64;
#pragma unroll
      for (int j = 0; j < 8; ++j) fd[j] = srcD[(size_t)j * DM];
      srcD += (size_t)32 * DM;
    }
    bf16x8 a[4], b[4];
#pragma unroll
    for (int i = 0; i < 4; ++i) a[i] = *(const bf16x8*)(bufc + offA[i]);
#pragma unroll
    for (int j = 0; j < 4; ++j) b[j] = *(const bf16x8*)(bufc + offBr[j]);
#pragma unroll
    for (int i = 0; i < 4; ++i)
#pragma unroll
      for (int j = 0; j < 4; ++j)
        acc[i][j] = __builtin_amdgcn_mfma_f32_16x16x32_bf16(a[i], b[j], acc[i][j], 0, 0, 0);
    if (more) {
      uint4 dp;
      dp.x = pack2(fd[0], fd[1]); dp.y = pack2(fd[2], fd[3]);
      dp.z = pack2(fd[4], fd[5]); dp.w = pack2(fd[6], fd[7]);
      *(uint4*)(bufn + 16384 + offBw) = dp;
    }
    __syncthreads();
  }

  const int colbase = tn * 128 + wn * 64;
  const int rlane = (lane >> 4) * 4;
  const int clane = lane & 15;
#pragma unroll
  for (int i = 0; i < 4; ++i) {
#pragma unroll
    for (int rr = 0; rr < 4; ++rr) {
      int rowIn = wm * 64 + i * 16 + rlane + rr;
      if (tm * 256 + rowIn < Me) {
        int tok = tlist[prowbase + rowIn];
        float* yp = y + (size_t)tok * DM + colbase + clane;
#pragma unroll
        for (int j = 0; j < 4; ++j) atomicAdd(&yp[j * 16], acc[i][j][rr]);
      }
    }
  }
}

extern "C" void kernel_launch(void* const* d_in, const int* in_sizes, int n_in,
                              void* d_out, int out_size, void* d_ws, size_t ws_size,
                              hipStream_t stream)
{
  const float* x   = (const float*)d_in[0];
  const float* wgw = (const float*)d_in[1];
  const float* wgb = (const float*)d_in[2];
  const float* Wu  = (const float*)d_in[3];
  const float* Wv  = (const float*)d_in[4];
  const float* Wd  = (const float*)d_in[5];
  float* out = (float*)d_out;

  char* ws = (char*)d_ws;
  int*   counts = (int*)(ws + 0);                         // 8 ints
  int*   eidx   = (int*)(ws + 256);                       // 4096
  float* gatep  = (float*)(ws + 16640);                   // 4096
  int*   prow   = (int*)(ws + 33024);                     // 4096
  float* cepart = (float*)(ws + 49408);                   // 1024*8
  int*   tlist  = (int*)(ws + 82176);                     // 5120 (padded rows)
  float* gate_b = (float*)(ws + 102656);                  // 5120
  unsigned short* xb  = (unsigned short*)(ws + 123136);   // 5120*768 bf16
  unsigned short* h   = (unsigned short*)(ws + 7987456);  // 5120*2048 bf16

  k_gate<<<1024, 256, 0, stream>>>(x, wgw, wgb, eidx, gatep, cepart);
  k_count<<<1, 256, 0, stream>>>(eidx, gatep, cepart, prow, tlist, gate_b,
                                 counts, out + (size_t)TOK * DM);
  k2_scatter_zero<<<1536, 256, 0, stream>>>(x, prow, xb, out);
  k_ffn1<<<2048, 512, 0, stream>>>(Wu, Wv, xb, gate_b, counts, h);
  k_ffn2<<<3072, 512, 0, stream>>>(Wd, h, counts, tlist, out);
}

// Round 2
// 347.759 us; speedup vs baseline: 1.0450x; 1.0450x over previous
//
#include <hip/hip_runtime.h>
#include <cstdint>
#include <cstddef>

#define TOK 4096
#define DM 768
#define HID 2048
#define NE 8

typedef __attribute__((ext_vector_type(8))) short bf16x8;
typedef __attribute__((ext_vector_type(4))) float f32x4;

// async global->LDS: dest = wave-uniform base + lane*16; SOURCE is per-lane.
#define ASYNC16(GP, LP) \
  __builtin_amdgcn_global_load_lds((__attribute__((address_space(1))) void*)(GP), \
                                   (__attribute__((address_space(3))) void*)(LP), 16, 0, 0)

__device__ __forceinline__ unsigned short f2bf(float f) {
  unsigned int u = __float_as_uint(f);
  u += 0x7FFF + ((u >> 16) & 1);   // RNE
  return (unsigned short)(u >> 16);
}
__device__ __forceinline__ unsigned int pack2(float a, float b) {
  return (unsigned)f2bf(a) | ((unsigned)f2bf(b) << 16);
}
__device__ __forceinline__ int padded_off(const int* counts, int e) {
  int o = 0;
  for (int i = 0; i < e; ++i) o += (counts[i] + 127) & ~127;
  return o;
}

// ---------------- K_gate: gating only (NO atomics) ----------------
__global__ __launch_bounds__(256)
void k_gate(const float* __restrict__ x, const float* __restrict__ wgw,
            const float* __restrict__ wgb,
            int* __restrict__ eidx, float* __restrict__ gatep,
            float* __restrict__ cepart)
{
  __shared__ float ce_loc[4][NE];
  const int lane = threadIdx.x & 63;
  const int w = threadIdx.x >> 6;
  const int t = blockIdx.x * 4 + w;
  float acc[NE];
#pragma unroll
  for (int e = 0; e < NE; ++e) acc[e] = 0.f;
  const float* xr = x + (size_t)t * DM;
#pragma unroll
  for (int j = 0; j < DM / 64; ++j) {
    float xv = xr[j * 64 + lane];
#pragma unroll
    for (int e = 0; e < NE; ++e) acc[e] += xv * wgw[e * DM + j * 64 + lane];
  }
#pragma unroll
  for (int e = 0; e < NE; ++e) {
    float v = acc[e];
#pragma unroll
    for (int off = 32; off >= 1; off >>= 1) v += __shfl_xor(v, off);
    acc[e] = v + wgb[e];
  }
  float mx = acc[0]; int ai = 0;
#pragma unroll
  for (int e = 1; e < NE; ++e) if (acc[e] > mx) { mx = acc[e]; ai = e; }
  float p[NE]; float se = 0.f;
#pragma unroll
  for (int e = 0; e < NE; ++e) { p[e] = expf(acc[e] - mx); se += p[e]; }
  float inv = 1.f / se;
  if (lane == 0) {
#pragma unroll
    for (int e = 0; e < NE; ++e) ce_loc[w][e] = p[e] * inv;
    eidx[t] = ai;
    gatep[t] = p[ai] * inv;
  }
  __syncthreads();
  if (threadIdx.x < NE) {
    float s = ce_loc[0][threadIdx.x] + ce_loc[1][threadIdx.x]
            + ce_loc[2][threadIdx.x] + ce_loc[3][threadIdx.x];
    cepart[blockIdx.x * NE + threadIdx.x] = s;
  }
}

// ---------------- K_count: single-block counting sort + aux ----------------
__global__ __launch_bounds__(256)
void k_count(const int* __restrict__ eidx, const float* __restrict__ gatep,
             const float* __restrict__ cepart,
             int* __restrict__ prow_arr, int* __restrict__ tlist,
             float* __restrict__ gate_b, int* __restrict__ counts_g,
             float* __restrict__ aux_out)
{
  __shared__ int hist[256][NE];
  __shared__ float fs[256][NE];
  __shared__ int po_s[NE], cnt_s[NE];
  const int tid = threadIdx.x;
  int own[NE], v[NE], el[16];
#pragma unroll
  for (int e = 0; e < NE; ++e) own[e] = 0;
#pragma unroll
  for (int j = 0; j < 16; ++j) {
    el[j] = eidx[tid * 16 + j];
#pragma unroll
    for (int e = 0; e < NE; ++e) own[e] += (el[j] == e) ? 1 : 0;
  }
#pragma unroll
  for (int e = 0; e < NE; ++e) { v[e] = own[e]; hist[tid][e] = v[e]; }
  __syncthreads();
  for (int st = 1; st < 256; st <<= 1) {
    int add[NE];
#pragma unroll
    for (int e = 0; e < NE; ++e) add[e] = (tid >= st) ? hist[tid - st][e] : 0;
    __syncthreads();
#pragma unroll
    for (int e = 0; e < NE; ++e) { v[e] += add[e]; hist[tid][e] = v[e]; }
    __syncthreads();
  }
  if (tid == 0) {
    int o = 0;
#pragma unroll
    for (int e = 0; e < NE; ++e) {
      int c = hist[255][e];
      cnt_s[e] = c; counts_g[e] = c; po_s[e] = o;
      o += (c + 127) & ~127;
    }
  }
  __syncthreads();
  int run[NE];
#pragma unroll
  for (int e = 0; e < NE; ++e) run[e] = po_s[e] + v[e] - own[e];
#pragma unroll
  for (int j = 0; j < 16; ++j) {
    const int t = tid * 16 + j;
    const int e = el[j];
    int p = 0;
#pragma unroll
    for (int k = 0; k < NE; ++k) if (e == k) p = run[k]++;
    prow_arr[t] = p;
    tlist[p] = t;
    gate_b[p] = gatep[t];
  }
  // aux reduce
  float s[NE];
#pragma unroll
  for (int e = 0; e < NE; ++e) s[e] = 0.f;
  for (int bb = tid; bb < 1024; bb += 256)
#pragma unroll
    for (int e = 0; e < NE; ++e) s[e] += cepart[bb * NE + e];
#pragma unroll
  for (int e = 0; e < NE; ++e) fs[tid][e] = s[e];
  __syncthreads();
  for (int st = 128; st > 0; st >>= 1) {
    if (tid < st)
#pragma unroll
      for (int e = 0; e < NE; ++e) fs[tid][e] += fs[tid + st][e];
    __syncthreads();
  }
  if (tid == 0) {
    float aux = 0.f;
    for (int e = 0; e < NE; ++e)
      aux += ((float)cnt_s[e] / 4096.f) * (fs[0][e] / 4096.f);
    aux_out[0] = 0.05f * 8.f * aux;
  }
}

// ---------------- K2: scatter x rows (row-major bf16) + zero y ----------------
__global__ __launch_bounds__(256)
void k2_scatter_zero(const float* __restrict__ x, const int* __restrict__ prow_arr,
                     unsigned short* __restrict__ xb, float* __restrict__ y)
{
  const int b = blockIdx.x;
  if (b < 1024) {
    const int lane = threadIdx.x & 63;
    const int w = threadIdx.x >> 6;
    const int t = b * 4 + w;
    const int prow = prow_arr[t];
    const float4* src4 = (const float4*)(x + (size_t)t * DM);
    uint2* dst = (uint2*)(xb + (size_t)prow * DM);
#pragma unroll
    for (int c = 0; c < 3; ++c) {
      float4 v = src4[lane + c * 64];
      uint2 d; d.x = pack2(v.x, v.y); d.y = pack2(v.z, v.w);
      dst[lane + c * 64] = d;
    }
  } else {
    float4* y4 = (float4*)y;
    const int base = (b - 1024) * 1536 + threadIdx.x;
#pragma unroll
    for (int c = 0; c < 6; ++c) {
      float4 z; z.x = 0.f; z.y = 0.f; z.z = 0.f; z.w = 0.f;
      y4[base + c * 256] = z;
    }
  }
}

// Dense tile lookup: tile index -> (expert, tm) via prefix scan of
// ceil(counts[e]/256). Max total tiles = 4096/256 + 8 = 24.
__device__ __forceinline__ bool tile_lookup(const int* __restrict__ counts,
                                            int tile, int& e, int& tm) {
  int acc = 0, fe = -1, ftm = 0;
#pragma unroll
  for (int i = 0; i < NE; ++i) {
    int nt = (counts[i] + 255) >> 8;
    if (fe < 0 && tile < acc + nt) { fe = i; ftm = tile - acc; }
    acc += nt;
  }
  if (fe < 0) return false;
  e = fe; tm = ftm;
  return true;
}

// ---------------- FFN1: h = silu(x@Wu)*(x@Wv)*gate ----------------
// Fused fp32->bf16 conversion. 256M x 128N, BK=32, double-buffered.
// 512 threads = 8 waves (4m x 2n), wave tile 64x64.
// LDS per buffer: A 16KB | Bu 8KB | Bv 8KB  (2 buffers = 64KB).
// Grid: dense 1-D, bid = tile*16 + tn  (working bids contiguous -> spread
// across all XCDs/CUs; round-0's (e,tm,tn) grid put all work on ~32 CUs).
__global__ __launch_bounds__(512, 2)
void k_ffn1(const float* __restrict__ Wu, const float* __restrict__ Wv,
            const unsigned short* __restrict__ xb, const float* __restrict__ gate_b,
            const int* __restrict__ counts, unsigned short* __restrict__ h)
{
  const int bid = blockIdx.x;
  const int tn = bid & 15;
  const int tile = bid >> 4;
  int e, tm;
  if (!tile_lookup(counts, tile, e, tm)) return;
  const int Me = counts[e];
  const int prowbase = padded_off(counts, e) + tm * 256;

  __shared__ __align__(16) char Sh[65536];   // [2][A 16K | Bu 8K | Bv 8K]

  const int tid = threadIdx.x;
  const int lane = tid & 63;
  const int w = tid >> 6;
  const int wm = w >> 1, wn = w & 1;

  // ---- A async staging: 2 chunks of 1KB per wave (16 chunks = 256 rows x 32k)
  const int c0 = w * 2, c1 = w * 2 + 1;
  const int mA0 = c0 * 16 + (lane >> 2), sA0 = lane & 3;
  const int ko0 = (sA0 - mA0 - (mA0 >> 2)) & 3;
  const char* aSrc0 = (const char*)xb + (size_t)(prowbase + mA0) * (DM * 2) + ko0 * 16;
  const int mA1 = c1 * 16 + (lane >> 2), sA1 = lane & 3;
  const int ko1 = (sA1 - mA1 - (mA1 >> 2)) & 3;
  const char* aSrc1 = (const char*)xb + (size_t)(prowbase + mA1) * (DM * 2) + ko1 * 16;

  // ---- B reg-staging: thread -> (nloc, koW); 8 coalesced fp32 loads (256B/wave)
  const int koW = w & 3;
  const int nloc = (w >> 2) * 64 + lane;
  const unsigned offBw = (unsigned)(nloc * 4 + ((koW + nloc + (nloc >> 2)) & 3)) * 16;
  const int ncol = tn * 128 + nloc;
  const float* srcU = Wu + (size_t)e * DM * HID + (size_t)(koW * 8) * HID + ncol;
  const float* srcV = Wv + (size_t)e * DM * HID + (size_t)(koW * 8) * HID + ncol;

  // ---- compute-side LDS read offsets
  const int lc = lane & 15, q = lane >> 4;
  unsigned offA[4], offU[4], offV[4];
#pragma unroll
  for (int i = 0; i < 4; ++i) {
    int m = wm * 64 + i * 16 + lc;
    offA[i] = (unsigned)(m * 4 + ((q + m + (m >> 2)) & 3)) * 16;
    int n = wn * 64 + i * 16 + lc;
    unsigned ob = (unsigned)(n * 4 + ((q + n + (n >> 2)) & 3)) * 16;
    offU[i] = 16384u + ob;
    offV[i] = 24576u + ob;
  }

  f32x4 accU[4][4], accV[4][4];
#pragma unroll
  for (int i = 0; i < 4; ++i)
#pragma unroll
    for (int j = 0; j < 4; ++j)
#pragma unroll
      for (int k = 0; k < 4; ++k) { accU[i][j][k] = 0.f; accV[i][j][k] = 0.f; }

  float fu[8], fv[8];
  // ---- prologue: stage step 0 into buffer 0
  ASYNC16(aSrc0, Sh + c0 * 1024); aSrc0 += 64;
  ASYNC16(aSrc1, Sh + c1 * 1024); aSrc1 += 64;
#pragma unroll
  for (int j = 0; j < 8; ++j) { fu[j] = srcU[(size_t)j * HID]; fv[j] = srcV[(size_t)j * HID]; }
  srcU += (size_t)32 * HID; srcV += (size_t)32 * HID;
  {
    uint4 up, vp;
    up.x = pack2(fu[0], fu[1]); up.y = pack2(fu[2], fu[3]);
    up.z = pack2(fu[4], fu[5]); up.w = pack2(fu[6], fu[7]);
    vp.x = pack2(fv[0], fv[1]); vp.y = pack2(fv[2], fv[3]);
    vp.z = pack2(fv[4], fv[5]); vp.w = pack2(fv[6], fv[7]);
    *(uint4*)(Sh + 16384 + offBw) = up;
    *(uint4*)(Sh + 24576 + offBw) = vp;
  }
  __syncthreads();

  for (int kt = 0; kt < 24; ++kt) {
    char* bufc = Sh + (unsigned)(kt & 1) * 32768u;
    char* bufn = Sh + (unsigned)((kt + 1) & 1) * 32768u;
    const bool more = (kt + 1) < 24;
    if (more) {                       // issue next step's loads BEFORE compute
      ASYNC16(aSrc0, bufn + c0 * 1024); aSrc0 += 64;
      ASYNC16(aSrc1, bufn + c1 * 1024); aSrc1 += 64;
#pragma unroll
      for (int j = 0; j < 8; ++j) { fu[j] = srcU[(size_t)j * HID]; fv[j] = srcV[(size_t)j * HID]; }
      srcU += (size_t)32 * HID; srcV += (size_t)32 * HID;
    }
    bf16x8 a[4], bu[4], bv[4];
#pragma unroll
    for (int i = 0; i < 4; ++i) a[i] = *(const bf16x8*)(bufc + offA[i]);
#pragma unroll
    for (int j = 0; j < 4; ++j) {
      bu[j] = *(const bf16x8*)(bufc + offU[j]);
      bv[j] = *(const bf16x8*)(bufc + offV[j]);
    }
#pragma unroll
    for (int i = 0; i < 4; ++i)
#pragma unroll
      for (int j = 0; j < 4; ++j) {
        accU[i][j] = __builtin_amdgcn_mfma_f32_16x16x32_bf16(a[i], bu[j], accU[i][j], 0, 0, 0);
        accV[i][j] = __builtin_amdgcn_mfma_f32_16x16x32_bf16(a[i], bv[j], accV[i][j], 0, 0, 0);
      }
    if (more) {                       // convert + write next buffer (latency hidden by MFMA)
      uint4 up, vp;
      up.x = pack2(fu[0], fu[1]); up.y = pack2(fu[2], fu[3]);
      up.z = pack2(fu[4], fu[5]); up.w = pack2(fu[6], fu[7]);
      vp.x = pack2(fv[0], fv[1]); vp.y = pack2(fv[2], fv[3]);
      vp.z = pack2(fv[4], fv[5]); vp.w = pack2(fv[6], fv[7]);
      *(uint4*)(bufn + 16384 + offBw) = up;
      *(uint4*)(bufn + 24576 + offBw) = vp;
    }
    __syncthreads();
  }

  const int colbase = tn * 128 + wn * 64;
  const int rlane = (lane >> 4) * 4;
  const int clane = lane & 15;
#pragma unroll
  for (int i = 0; i < 4; ++i) {
#pragma unroll
    for (int rr = 0; rr < 4; ++rr) {
      int rowIn = wm * 64 + i * 16 + rlane + rr;
      if (tm * 256 + rowIn < Me) {
        int prow = prowbase + rowIn;
        float g = gate_b[prow];
        unsigned short* hp = h + (size_t)prow * HID + colbase + clane;
#pragma unroll
        for (int j = 0; j < 4; ++j) {
          float u_ = accU[i][j][rr];
          float v_ = accV[i][j][rr];
          float sv = u_ / (1.f + expf(-u_));
          hp[j * 16] = f2bf(sv * v_ * g);
        }
      }
    }
  }
}

// ---------------- FFN2: y += h @ Wd (split-K=4, atomic f32) ----------------
// Fused fp32->bf16 conversion. 256M x 128N, BK=32, double-buffered.
// LDS per buffer: A 16KB | B 8KB  (2 buffers = 48KB).
// Grid: dense 1-D, bid = tile*24 + (sk*6 + tn).
__global__ __launch_bounds__(512, 2)
void k_ffn2(const float* __restrict__ Wd, const unsigned short* __restrict__ h,
            const int* __restrict__ counts, const int* __restrict__ tlist,
            float* __restrict__ y)
{
  const int bid = blockIdx.x;
  const int inner = bid % 24;
  const int tn = inner % 6;
  const int sk = inner / 6;              // split-K 0..3
  const int tile = bid / 24;
  int e, tm;
  if (!tile_lookup(counts, tile, e, tm)) return;
  const int Me = counts[e];
  const int prowbase = padded_off(counts, e) + tm * 256;

  __shared__ __align__(16) char Sh[49152];   // [2][A 16K | B 8K]

  const int tid = threadIdx.x;
  const int lane = tid & 63;
  const int w = tid >> 6;
  const int wm = w >> 1, wn = w & 1;

  // ---- A async staging (h rows, bf16), split-K window
  const int c0 = w * 2, c1 = w * 2 + 1;
  const int mA0 = c0 * 16 + (lane >> 2), sA0 = lane & 3;
  const int ko0 = (sA0 - mA0 - (mA0 >> 2)) & 3;
  const char* aSrc0 = (const char*)h + (size_t)(prowbase + mA0) * (HID * 2) + sk * 1024 + ko0 * 16;
  const int mA1 = c1 * 16 + (lane >> 2), sA1 = lane & 3;
  const int ko1 = (sA1 - mA1 - (mA1 >> 2)) & 3;
  const char* aSrc1 = (const char*)h + (size_t)(prowbase + mA1) * (HID * 2) + sk * 1024 + ko1 * 16;

  // ---- B reg-staging: one 16B unit per thread
  const int nloc = tid & 127;
  const int koW = tid >> 7;              // 0..3
  const unsigned offBw = (unsigned)(nloc * 4 + ((koW + nloc + (nloc >> 2)) & 3)) * 16;
  const int ncol = tn * 128 + nloc;
  const float* srcD = Wd + (size_t)e * HID * DM + (size_t)(sk * 512 + koW * 8) * DM + ncol;

  const int lc = lane & 15, q = lane >> 4;
  unsigned offA[4], offBr[4];
#pragma unroll
  for (int i = 0; i < 4; ++i) {
    int m = wm * 64 + i * 16 + lc;
    offA[i] = (unsigned)(m * 4 + ((q + m + (m >> 2)) & 3)) * 16;
    int n = wn * 64 + i * 16 + lc;
    offBr[i] = 16384u + (unsigned)(n * 4 + ((q + n + (n >> 2)) & 3)) * 16;
  }

  f32x4 acc[4][4];
#pragma unroll
  for (int i = 0; i < 4; ++i)
#pragma unroll
    for (int j = 0; j < 4; ++j)
#pragma unroll
      for (int k = 0; k < 4; ++k) acc[i][j][k] = 0.f;

  float fd[8];
  // ---- prologue
  ASYNC16(aSrc0, Sh + c0 * 1024); aSrc0 += 64;
  ASYNC16(aSrc1, Sh + c1 * 1024); aSrc1 += 64;
#pragma unroll
  for (int j = 0; j < 8; ++j) fd[j] = srcD[(size_t)j * DM];
  srcD += (size_t)32 * DM;
  {
    uint4 dp;
    dp.x = pack2(fd[0], fd[1]); dp.y = pack2(fd[2], fd[3]);
    dp.z = pack2(fd[4], fd[5]); dp.w = pack2(fd[6], fd[7]);
    *(uint4*)(Sh + 16384 + offBw) = dp;
  }
  __syncthreads();

  for (int kt = 0; kt < 16; ++kt) {
    char* bufc = Sh + (unsigned)(kt & 1) * 24576u;
    char* bufn = Sh + (unsigned)((kt + 1) & 1) * 24576u;
    const bool more = (kt + 1) < 16;
    if (more) {
      ASYNC16(aSrc0, bufn + c0 * 1024); aSrc0 += 64;
      ASYNC16(aSrc1, bufn + c1 * 1024); aSrc1 += 64;
#pragma unroll
      for (int j = 0; j < 8; ++j) fd[j] = srcD[(size_t)j * DM];
      srcD += (size_t)32 * DM;
    }
    bf16x8 a[4], b[4];
#pragma unroll
    for (int i = 0; i < 4; ++i) a[i] = *(const bf16x8*)(bufc + offA[i]);
#pragma unroll
    for (int j = 0; j < 4; ++j) b[j] = *(const bf16x8*)(bufc + offBr[j]);
#pragma unroll
    for (int i = 0; i < 4; ++i)
#pragma unroll
      for (int j = 0; j < 4; ++j)
        acc[i][j] = __builtin_amdgcn_mfma_f32_16x16x32_bf16(a[i], b[j], acc[i][j], 0, 0, 0);
    if (more) {
      uint4 dp;
      dp.x = pack2(fd[0], fd[1]); dp.y = pack2(fd[2], fd[3]);
      dp.z = pack2(fd[4], fd[5]); dp.w = pack2(fd[6], fd[7]);
      *(uint4*)(bufn + 16384 + offBw) = dp;
    }
    __syncthreads();
  }

  const int colbase = tn * 128 + wn * 64;
  const int rlane = (lane >> 4) * 4;
  const int clane = lane & 15;
#pragma unroll
  for (int i = 0; i < 4; ++i) {
#pragma unroll
    for (int rr = 0; rr < 4; ++rr) {
      int rowIn = wm * 64 + i * 16 + rlane + rr;
      if (tm * 256 + rowIn < Me) {
        int tok = tlist[prowbase + rowIn];
        float* yp = y + (size_t)tok * DM + colbase + clane;
#pragma unroll
        for (int j = 0; j < 4; ++j) atomicAdd(&yp[j * 16], acc[i][j][rr]);
      }
    }
  }
}

extern "C" void kernel_launch(void* const* d_in, const int* in_sizes, int n_in,
                              void* d_out, int out_size, void* d_ws, size_t ws_size,
                              hipStream_t stream)
{
  const float* x   = (const float*)d_in[0];
  const float* wgw = (const float*)d_in[1];
  const float* wgb = (const float*)d_in[2];
  const float* Wu  = (const float*)d_in[3];
  const float* Wv  = (const float*)d_in[4];
  const float* Wd  = (const float*)d_in[5];
  float* out = (float*)d_out;

  char* ws = (char*)d_ws;
  int*   counts = (int*)(ws + 0);                         // 8 ints
  int*   eidx   = (int*)(ws + 256);                       // 4096
  float* gatep  = (float*)(ws + 16640);                   // 4096
  int*   prow   = (int*)(ws + 33024);                     // 4096
  float* cepart = (float*)(ws + 49408);                   // 1024*8
  int*   tlist  = (int*)(ws + 82176);                     // 5120 (padded rows)
  float* gate_b = (float*)(ws + 102656);                  // 5120
  unsigned short* xb  = (unsigned short*)(ws + 123136);   // 5120*768 bf16
  unsigned short* h   = (unsigned short*)(ws + 7987456);  // 5120*2048 bf16

  k_gate<<<1024, 256, 0, stream>>>(x, wgw, wgb, eidx, gatep, cepart);
  k_count<<<1, 256, 0, stream>>>(eidx, gatep, cepart, prow, tlist, gate_b,
                                 counts, out + (size_t)TOK * DM);
  k2_scatter_zero<<<1536, 256, 0, stream>>>(x, prow, xb, out);
  k_ffn1<<<24 * 16, 512, 0, stream>>>(Wu, Wv, xb, gate_b, counts, h);
  k_ffn2<<<24 * 24, 512, 0, stream>>>(Wd, h, counts, tlist, out);
}